// Round 5
// baseline (288.865 us; speedup 1.0000x reference)
//
#include <hip/hip_runtime.h>

#define BB 8
#define MM 4096
#define EE 1024
#define DD 128
#define NCAT 64

typedef __attribute__((ext_vector_type(8))) short bf16x8;
typedef __attribute__((ext_vector_type(4))) float f32x4;

// pack two f32 -> (bf16(hi)<<16)|bf16(lo), truncation, 1 instr (v_perm_b32)
__device__ __forceinline__ unsigned pk(float lo, float hi) {
    return __builtin_amdgcn_perm(__float_as_uint(hi), __float_as_uint(lo), 0x07060302u);
}

// stats layout (floats): colsum[1024] | praw[1024] | sumA[8] | pad | done(int @2072)
#define ST_COLSUM 0
#define ST_PRAW   1024
#define ST_SUMA   2048
#define ST_DONE   2072
#define ST_TOTAL  2080

// ---------------------------------------------------------------------------
// K1: agg = inc^T @ nf per batch via bf16 MFMA (inc binary -> bf16 exact;
// nf split hi/lo bf16 -> ~fp24). Block tile 64e x 128d, 4 waves (2x2),
// wave tile 32e x 64d = 2x4 frags of 16x16x32. Grid 512 = b8 x et16 x ks4,
// 2 blocks/CU for phase overlap + HBM latency hiding. LDS subtile layout
// [kgrp][col][8 shorts]: all staging writes / frag reads are 16B,
// conflict-free. 1-deep register prefetch. Block 0 also zeroes the stats
// region (consumed only by later kernels; stream order guarantees safety).
// ---------------------------------------------------------------------------
__global__ __launch_bounds__(256, 2) void k_magg(const float* __restrict__ nf,
                                                 const float* __restrict__ inc,
                                                 float* __restrict__ part,
                                                 float* __restrict__ stats) {
    int bid = blockIdx.x;               // b + 8*(et + 16*ks)
    int tid = threadIdx.x;
    if (bid == 0) {
        for (int i = tid; i < ST_TOTAL; i += 256) stats[i] = 0.0f;
    }
    int b  = bid & 7;
    int et = (bid >> 3) & 15;
    int ks = bid >> 7;

    __shared__ __align__(16) unsigned short As[4][64][8];    // 4 KB
    __shared__ __align__(16) unsigned short Bh[4][128][8];   // 8 KB
    __shared__ __align__(16) unsigned short Bl[4][128][8];   // 8 KB

    int lane = tid & 63;
    int w    = tid >> 6;
    int we   = (w & 1) * 32;
    int wd   = (w >> 1) * 64;

    int ecolA = tid & 63;               // e column staged by this thread
    int mgrpA = tid >> 6;               // 0..3 -> 8-m group (= kgroup)
    int dcolB = tid & 127;              // d column staged
    int mhB   = tid >> 7;               // 0..1 -> 16-m half (= 2 kgroups)

    long m0 = (long)ks * 1024;
    const float* incp = inc + ((long)b * MM + m0) * EE + et * 64 + ecolA;
    const float* nfp  = nf  + ((long)b * MM + m0) * DD + dcolB;

    f32x4 acc[2][4];
#pragma unroll
    for (int i = 0; i < 2; ++i)
#pragma unroll
        for (int j = 0; j < 4; ++j) acc[i][j] = (f32x4)(0.0f);

    float ra[8], rb[16];

#define LOADM(t) do {                                                         \
    _Pragma("unroll")                                                         \
    for (int j2 = 0; j2 < 8; ++j2)                                            \
        ra[j2] = incp[(long)((t) * 32 + mgrpA * 8 + j2) * EE];                \
    _Pragma("unroll")                                                         \
    for (int j2 = 0; j2 < 16; ++j2)                                           \
        rb[j2] = nfp[(long)((t) * 32 + mhB * 16 + j2) * DD];                  \
} while (0)

#define STOREM() do {                                                         \
    unsigned ua[4];                                                           \
    _Pragma("unroll")                                                         \
    for (int q = 0; q < 4; ++q) ua[q] = pk(ra[2 * q], ra[2 * q + 1]);         \
    *(uint4*)&As[mgrpA][ecolA][0] = make_uint4(ua[0], ua[1], ua[2], ua[3]);   \
    unsigned uh[8], ul[8];                                                    \
    _Pragma("unroll")                                                         \
    for (int q = 0; q < 8; ++q) {                                             \
        float x0 = rb[2 * q], x1 = rb[2 * q + 1];                             \
        uh[q] = pk(x0, x1);                                                   \
        float h0 = __uint_as_float(__float_as_uint(x0) & 0xffff0000u);        \
        float h1 = __uint_as_float(__float_as_uint(x1) & 0xffff0000u);        \
        ul[q] = pk(x0 - h0, x1 - h1);                                         \
    }                                                                         \
    *(uint4*)&Bh[2 * mhB][dcolB][0]     = make_uint4(uh[0], uh[1], uh[2], uh[3]); \
    *(uint4*)&Bh[2 * mhB + 1][dcolB][0] = make_uint4(uh[4], uh[5], uh[6], uh[7]); \
    *(uint4*)&Bl[2 * mhB][dcolB][0]     = make_uint4(ul[0], ul[1], ul[2], ul[3]); \
    *(uint4*)&Bl[2 * mhB + 1][dcolB][0] = make_uint4(ul[4], ul[5], ul[6], ul[7]); \
} while (0)

    LOADM(0);
    for (int t = 0; t < 32; ++t) {
        STOREM();
        if (t + 1 < 32) LOADM(t + 1);   // in flight across compute of t
        __syncthreads();
        {
            int kg = lane >> 4, rr = lane & 15;
            bf16x8 af[2];
#pragma unroll
            for (int i = 0; i < 2; ++i)
                af[i] = *(const bf16x8*)&As[kg][we + i * 16 + rr][0];
#pragma unroll
            for (int j = 0; j < 4; ++j) {
                bf16x8 bh = *(const bf16x8*)&Bh[kg][wd + j * 16 + rr][0];
                bf16x8 bl = *(const bf16x8*)&Bl[kg][wd + j * 16 + rr][0];
#pragma unroll
                for (int i = 0; i < 2; ++i) {
                    acc[i][j] = __builtin_amdgcn_mfma_f32_16x16x32_bf16(af[i], bh, acc[i][j], 0, 0, 0);
                    acc[i][j] = __builtin_amdgcn_mfma_f32_16x16x32_bf16(af[i], bl, acc[i][j], 0, 0, 0);
                }
            }
        }
        __syncthreads();
    }

    const long PS = (long)BB * EE * DD;
    float* pp = part + (long)ks * PS + ((long)b * EE + et * 64) * DD;
#pragma unroll
    for (int i = 0; i < 2; ++i)
#pragma unroll
        for (int j = 0; j < 4; ++j) {
            int e = we + i * 16 + ((lane >> 4) << 2);
            int d = wd + j * 16 + (lane & 15);
#pragma unroll
            for (int r = 0; r < 4; ++r)
                pp[(long)(e + r) * DD + d] = acc[i][j][r];
        }
#undef LOADM
#undef STOREM
}

// ---------------------------------------------------------------------------
// K2: combine 4 k-split partials -> agg; esc = exp(agg @ W_att^T); fused
// column-sum: colsum[b][d] += sum_{e in block} esc. No max subtraction
// (|score| <~ 45 -> exp fits fp32 with huge headroom).
// ---------------------------------------------------------------------------
__global__ __launch_bounds__(256) void k_score(const float* __restrict__ part,
                                               float* __restrict__ agg,
                                               const float* __restrict__ W,
                                               float* __restrict__ esc,
                                               float* __restrict__ stats) {
    __shared__ float Wt[128][129];
    __shared__ float xt[16][128];
    __shared__ float cred[2][128];
    float* colsum = stats + ST_COLSUM;
    int tid = threadIdx.x;
    for (int t = tid; t < 128 * 128; t += 256) Wt[t & 127][t >> 7] = W[t];
    long r0 = (long)blockIdx.x * 16;
    const long PS = (long)BB * EE * DD;
    for (int t = tid; t < 2048; t += 256) {
        long off = r0 * 128 + t;
        float v = part[off] + part[off + PS] + part[off + 2 * PS] + part[off + 3 * PS];
        xt[t >> 7][t & 127] = v;
        agg[off] = v;
    }
    __syncthreads();
    int j = tid & 127, half = tid >> 7;
    float acc[8] = {0, 0, 0, 0, 0, 0, 0, 0};
    for (int k = 0; k < 128; k += 4) {
        float w0 = Wt[k][j], w1 = Wt[k + 1][j], w2 = Wt[k + 2][j], w3 = Wt[k + 3][j];
#pragma unroll
        for (int el = 0; el < 8; ++el) {
            float4 x4 = *(const float4*)&xt[half * 8 + el][k];
            acc[el] += x4.x * w0; acc[el] += x4.y * w1;
            acc[el] += x4.z * w2; acc[el] += x4.w * w3;
        }
    }
    float csum = 0.0f;
#pragma unroll
    for (int el = 0; el < 8; ++el) {
        float es = __expf(acc[el]);
        esc[(r0 + half * 8 + el) * 128 + j] = es;
        csum += es;
    }
    cred[half][j] = csum;
    __syncthreads();
    if (half == 0) {
        int b = (int)(r0 >> 10);
        atomicAdd(&colsum[b * DD + j], cred[0][j] + cred[1][j]);
    }
}

// ---------------------------------------------------------------------------
// K3: ef-rows = (esc*rinv*agg) @ W_proj^T in registers (never stored);
// a_r = ef_r . ec_att -> ea = exp(a_r); fused pooling via atomics:
// praw[b][d] += sum_r ea_r * ef[r][d], sumA[b] += sum_r ea_r.
// The LAST block (device-scope done-counter) then re-reads praw/sumA with
// coherent atomic-reads and computes the entire output tail:
// pooled = praw/sumA; out = pooled@ec_pw^T + b; logits = out@fc^T + fc_b.
// ---------------------------------------------------------------------------
__global__ __launch_bounds__(256) void k_proj(const float* __restrict__ esc,
                                              const float* __restrict__ agg,
                                              const float* __restrict__ W,
                                              const float* __restrict__ att,
                                              float* __restrict__ stats,
                                              const float* __restrict__ ec_pw,
                                              const float* __restrict__ ec_pb,
                                              const float* __restrict__ fc_w,
                                              const float* __restrict__ fc_b,
                                              float* __restrict__ out) {
    __shared__ float Wt[128][129];
    __shared__ float xt[16][128];
    __shared__ float ared[4][8];
    __shared__ float aex[16];
    __shared__ float pred[2][128];
    __shared__ float pall[1024];
    __shared__ float sall[8];
    __shared__ float outv[128];
    __shared__ int lastflag;
    float* colsum = stats + ST_COLSUM;
    float* praw   = stats + ST_PRAW;
    float* sumA   = stats + ST_SUMA;
    int*   done   = (int*)(stats + ST_DONE);
    int tid = threadIdx.x;
    for (int t = tid; t < 128 * 128; t += 256) Wt[t & 127][t >> 7] = W[t];
    long r0 = (long)blockIdx.x * 16;
    int b = (int)(r0 >> 10);
    float rinv = 1.0f / colsum[b * DD + (tid & 127)];
    for (int t = tid; t < 2048; t += 256) {
        long off = r0 * 128 + t;
        xt[t >> 7][t & 127] = esc[off] * rinv * agg[off];
    }
    __syncthreads();
    int j = tid & 127, half = tid >> 7;
    float acc[8] = {0, 0, 0, 0, 0, 0, 0, 0};
    for (int k = 0; k < 128; k += 4) {
        float w0 = Wt[k][j], w1 = Wt[k + 1][j], w2 = Wt[k + 2][j], w3 = Wt[k + 3][j];
#pragma unroll
        for (int el = 0; el < 8; ++el) {
            float4 x4 = *(const float4*)&xt[half * 8 + el][k];
            acc[el] += x4.x * w0; acc[el] += x4.y * w1;
            acc[el] += x4.z * w2; acc[el] += x4.w * w3;
        }
    }
    // a_r = sum_j ef[r][j] * att[j]
    float av = att[j];
    float contrib[8];
#pragma unroll
    for (int el = 0; el < 8; ++el) contrib[el] = acc[el] * av;
#pragma unroll
    for (int off2 = 32; off2 > 0; off2 >>= 1)
#pragma unroll
        for (int el = 0; el < 8; ++el)
            contrib[el] += __shfl_xor(contrib[el], off2, 64);
    int lane = tid & 63, wv = tid >> 6;
    if (lane == 0)
#pragma unroll
        for (int el = 0; el < 8; ++el) ared[wv][el] = contrib[el];
    __syncthreads();
    if (tid < 16) {
        int hh = tid >> 3, el = tid & 7;
        aex[tid] = __expf(ared[hh * 2][el] + ared[hh * 2 + 1][el]);
    }
    __syncthreads();
    if (tid == 0) {
        float s = 0.0f;
#pragma unroll
        for (int i = 0; i < 16; ++i) s += aex[i];
        atomicAdd(&sumA[b], s);
    }
    float p = 0.0f;
#pragma unroll
    for (int el = 0; el < 8; ++el) p += aex[half * 8 + el] * acc[el];
    pred[half][j] = p;
    __syncthreads();
    if (half == 0) atomicAdd(&praw[b * DD + j], pred[0][j] + pred[1][j]);

    // ---- last-block output tail ----
    __syncthreads();                 // drains all this block's vmem (incl. atomics)
    if (tid == 0) {
        __threadfence();
        lastflag = (atomicAdd(done, 1) == (int)gridDim.x - 1);
    }
    __syncthreads();
    if (!lastflag) return;
    // coherent re-read of the accumulators (atomic read bypasses stale L2)
#pragma unroll
    for (int i = 0; i < 4; ++i) pall[tid + 256 * i] = atomicAdd(&praw[tid + 256 * i], 0.0f);
    if (tid < 8) sall[tid] = atomicAdd(&sumA[tid], 0.0f);
    __syncthreads();
    for (int b2 = 0; b2 < BB; ++b2) {
        if (tid < 128) {
            float ri2 = 1.0f / sall[b2];
            const float* wr = ec_pw + tid * DD;
            const float* pb = &pall[b2 * DD];
            float o = 0.0f;
            for (int k = 0; k < DD; ++k) o += pb[k] * wr[k];
            outv[tid] = o * ri2 + ec_pb[tid];
        }
        __syncthreads();
        if (tid < NCAT) {
            float o2 = fc_b[tid];
            const float* wr2 = fc_w + tid * DD;
            for (int k = 0; k < DD; ++k) o2 += outv[k] * wr2[k];
            out[b2 * NCAT + tid] = o2;
        }
        __syncthreads();
    }
}

// ---------------------------------------------------------------------------
extern "C" void kernel_launch(void* const* d_in, const int* in_sizes, int n_in,
                              void* d_out, int out_size, void* d_ws, size_t ws_size,
                              hipStream_t stream) {
    const float* nf     = (const float*)d_in[0];
    const float* inc    = (const float*)d_in[1];
    const float* W_att  = (const float*)d_in[2];
    const float* W_proj = (const float*)d_in[3];
    const float* ec_att = (const float*)d_in[4];
    const float* ec_pw  = (const float*)d_in[5];
    const float* ec_pb  = (const float*)d_in[6];
    const float* fc_w   = (const float*)d_in[7];
    const float* fc_b   = (const float*)d_in[8];
    float* out = (float*)d_out;

    const long PS = (long)BB * EE * DD;                      // 1M floats
    char* ws = (char*)d_ws;
    float* part  = (float*)ws;                               // 16 MB (4 k-splits)
    float* agg   = (float*)(ws + 4 * PS * 4);                // 4 MB
    float* esc   = agg + PS;                                 // 4 MB
    float* stats = esc + PS;                                 // ST_TOTAL floats

    k_magg<<<512, 256, 0, stream>>>(nf, inc, part, stats);
    k_score<<<(BB * EE) / 16, 256, 0, stream>>>(part, agg, W_att, esc, stats);
    k_proj<<<(BB * EE) / 16, 256, 0, stream>>>(esc, agg, W_proj, ec_att, stats,
                                               ec_pw, ec_pb, fc_w, fc_b, out);
    k_out_unused:;
}